// Round 1
// baseline (899.327 us; speedup 1.0000x reference)
//
#include <hip/hip_runtime.h>
#include <math.h>

#define D_IN   128
#define H_DIM  32
#define OUT_DIM 3

// ---------------- degree / norm ----------------

__global__ void k_init_deg(float* deg, int n) {
    int i = blockIdx.x * blockDim.x + threadIdx.x;
    if (i < n) deg[i] = 1.0f;   // self-loop counted as +1
}

__global__ void k_count_deg(const int* __restrict__ dst, float* deg, int e) {
    int i = blockIdx.x * blockDim.x + threadIdx.x;
    if (i < e) atomicAdd(&deg[dst[i]], 1.0f);
}

__global__ void k_norm(float* deg, int n) {
    int i = blockIdx.x * blockDim.x + threadIdx.x;
    if (i < n) deg[i] = rsqrtf(deg[i]);
}

// ---------------- GEMM1: h1 = x @ W1 ; agg1 = h1 * norm^2 ----------------
// 256 threads/block, 256 nodes/block. Each thread: 4 nodes x 8 outputs.

__global__ __launch_bounds__(256) void k_gemm1(
    const float* __restrict__ x, const float* __restrict__ W1,
    const float* __restrict__ norm,
    float* __restrict__ h1, float* __restrict__ agg1, int n)
{
    __shared__ float Wl[D_IN * H_DIM];   // 16 KB
    for (int i = threadIdx.x; i < D_IN * H_DIM; i += 256) Wl[i] = W1[i];
    __syncthreads();

    const int jg = threadIdx.x & 3;      // output group -> j0 = jg*8
    const int ns = threadIdx.x >> 2;     // 0..63
    const int n0 = blockIdx.x * 256 + ns * 4;
    const int j0 = jg * 8;

    float acc[4][8];
#pragma unroll
    for (int m = 0; m < 4; ++m)
#pragma unroll
        for (int j = 0; j < 8; ++j) acc[m][j] = 0.0f;

    for (int k = 0; k < D_IN; k += 4) {
        float4 xv[4];
#pragma unroll
        for (int m = 0; m < 4; ++m) {
            int nn = n0 + m;
            xv[m] = (nn < n) ? *(const float4*)&x[(size_t)nn * D_IN + k]
                             : make_float4(0.f, 0.f, 0.f, 0.f);
        }
#pragma unroll
        for (int kk = 0; kk < 4; ++kk) {
            const float4 wa = *(const float4*)&Wl[(k + kk) * H_DIM + j0];
            const float4 wb = *(const float4*)&Wl[(k + kk) * H_DIM + j0 + 4];
#pragma unroll
            for (int m = 0; m < 4; ++m) {
                const float xs = (kk == 0) ? xv[m].x : (kk == 1) ? xv[m].y
                               : (kk == 2) ? xv[m].z : xv[m].w;
                acc[m][0] = fmaf(xs, wa.x, acc[m][0]);
                acc[m][1] = fmaf(xs, wa.y, acc[m][1]);
                acc[m][2] = fmaf(xs, wa.z, acc[m][2]);
                acc[m][3] = fmaf(xs, wa.w, acc[m][3]);
                acc[m][4] = fmaf(xs, wb.x, acc[m][4]);
                acc[m][5] = fmaf(xs, wb.y, acc[m][5]);
                acc[m][6] = fmaf(xs, wb.z, acc[m][6]);
                acc[m][7] = fmaf(xs, wb.w, acc[m][7]);
            }
        }
    }

#pragma unroll
    for (int m = 0; m < 4; ++m) {
        int nn = n0 + m;
        if (nn < n) {
            float nr = norm[nn];
            float n2 = nr * nr;
            float* hp = &h1[(size_t)nn * H_DIM + j0];
            float* ap = &agg1[(size_t)nn * H_DIM + j0];
            float4 v0 = make_float4(acc[m][0], acc[m][1], acc[m][2], acc[m][3]);
            float4 v1 = make_float4(acc[m][4], acc[m][5], acc[m][6], acc[m][7]);
            *(float4*)hp = v0;
            *(float4*)(hp + 4) = v1;
            *(float4*)ap = make_float4(v0.x * n2, v0.y * n2, v0.z * n2, v0.w * n2);
            *(float4*)(ap + 4) = make_float4(v1.x * n2, v1.y * n2, v1.z * n2, v1.w * n2);
        }
    }
}

// ---------------- GEMM2: h2 = relu(agg1 + b1) @ W2 ; agg2 = h2 * norm^2 ----

__global__ __launch_bounds__(256) void k_gemm2(
    const float* __restrict__ agg1, const float* __restrict__ b1,
    const float* __restrict__ W2, const float* __restrict__ norm,
    float* __restrict__ h2, float* __restrict__ agg2, int n)
{
    __shared__ float Wl[H_DIM * H_DIM];   // 4 KB
    __shared__ float bl[H_DIM];
    for (int i = threadIdx.x; i < H_DIM * H_DIM; i += 256) Wl[i] = W2[i];
    if (threadIdx.x < H_DIM) bl[threadIdx.x] = b1[threadIdx.x];
    __syncthreads();

    const int jg = threadIdx.x & 3;
    const int ns = threadIdx.x >> 2;
    const int n0 = blockIdx.x * 256 + ns * 4;
    const int j0 = jg * 8;

    float acc[4][8];
#pragma unroll
    for (int m = 0; m < 4; ++m)
#pragma unroll
        for (int j = 0; j < 8; ++j) acc[m][j] = 0.0f;

    for (int k = 0; k < H_DIM; k += 4) {
        float4 xv[4];
#pragma unroll
        for (int m = 0; m < 4; ++m) {
            int nn = n0 + m;
            if (nn < n) {
                float4 v = *(const float4*)&agg1[(size_t)nn * H_DIM + k];
                v.x = fmaxf(v.x + bl[k + 0], 0.f);
                v.y = fmaxf(v.y + bl[k + 1], 0.f);
                v.z = fmaxf(v.z + bl[k + 2], 0.f);
                v.w = fmaxf(v.w + bl[k + 3], 0.f);
                xv[m] = v;
            } else {
                xv[m] = make_float4(0.f, 0.f, 0.f, 0.f);
            }
        }
#pragma unroll
        for (int kk = 0; kk < 4; ++kk) {
            const float4 wa = *(const float4*)&Wl[(k + kk) * H_DIM + j0];
            const float4 wb = *(const float4*)&Wl[(k + kk) * H_DIM + j0 + 4];
#pragma unroll
            for (int m = 0; m < 4; ++m) {
                const float xs = (kk == 0) ? xv[m].x : (kk == 1) ? xv[m].y
                               : (kk == 2) ? xv[m].z : xv[m].w;
                acc[m][0] = fmaf(xs, wa.x, acc[m][0]);
                acc[m][1] = fmaf(xs, wa.y, acc[m][1]);
                acc[m][2] = fmaf(xs, wa.z, acc[m][2]);
                acc[m][3] = fmaf(xs, wa.w, acc[m][3]);
                acc[m][4] = fmaf(xs, wb.x, acc[m][4]);
                acc[m][5] = fmaf(xs, wb.y, acc[m][5]);
                acc[m][6] = fmaf(xs, wb.z, acc[m][6]);
                acc[m][7] = fmaf(xs, wb.w, acc[m][7]);
            }
        }
    }

#pragma unroll
    for (int m = 0; m < 4; ++m) {
        int nn = n0 + m;
        if (nn < n) {
            float nr = norm[nn];
            float n2 = nr * nr;
            float* hp = &h2[(size_t)nn * H_DIM + j0];
            float* ap = &agg2[(size_t)nn * H_DIM + j0];
            float4 v0 = make_float4(acc[m][0], acc[m][1], acc[m][2], acc[m][3]);
            float4 v1 = make_float4(acc[m][4], acc[m][5], acc[m][6], acc[m][7]);
            *(float4*)hp = v0;
            *(float4*)(hp + 4) = v1;
            *(float4*)ap = make_float4(v0.x * n2, v0.y * n2, v0.z * n2, v0.w * n2);
            *(float4*)(ap + 4) = make_float4(v1.x * n2, v1.y * n2, v1.z * n2, v1.w * n2);
        }
    }
}

// ---------------- scatter: agg[dst] += h[src] * norm[src]*norm[dst] --------
// 32 consecutive lanes handle one edge (one feature each).

__global__ __launch_bounds__(256) void k_scatter(
    const float* __restrict__ h, const float* __restrict__ norm,
    const int* __restrict__ src, const int* __restrict__ dst,
    float* __restrict__ agg, int e)
{
    long long gid = (long long)blockIdx.x * 256 + threadIdx.x;
    int ei = (int)(gid >> 5);
    int lane = threadIdx.x & 31;
    if (ei < e) {
        int s = src[ei], d = dst[ei];
        float coef = norm[s] * norm[d];
        float v = h[(size_t)s * H_DIM + lane] * coef;
        atomicAdd(&agg[(size_t)d * H_DIM + lane], v);
    }
}

// ---------------- final: out = sigmoid(relu(agg2 + b2) @ Wfc + bfc) --------

__global__ __launch_bounds__(256) void k_final(
    const float* __restrict__ agg2, const float* __restrict__ b2,
    const float* __restrict__ Wfc, const float* __restrict__ bfc,
    float* __restrict__ out, int n)
{
    __shared__ float Wl[H_DIM * OUT_DIM];
    __shared__ float bl[H_DIM];
    __shared__ float bfl[OUT_DIM];
    int t = threadIdx.x;
    if (t < H_DIM * OUT_DIM) Wl[t] = Wfc[t];
    if (t < H_DIM) bl[t] = b2[t];
    if (t < OUT_DIM) bfl[t] = bfc[t];
    __syncthreads();

    int i = blockIdx.x * 256 + t;
    if (i < n) {
        float a0 = bfl[0], a1 = bfl[1], a2 = bfl[2];
        const float* row = &agg2[(size_t)i * H_DIM];
#pragma unroll
        for (int j = 0; j < H_DIM; ++j) {
            float v = fmaxf(row[j] + bl[j], 0.f);
            a0 = fmaf(v, Wl[j * OUT_DIM + 0], a0);
            a1 = fmaf(v, Wl[j * OUT_DIM + 1], a1);
            a2 = fmaf(v, Wl[j * OUT_DIM + 2], a2);
        }
        out[(size_t)i * 3 + 0] = 1.0f / (1.0f + expf(-a0));
        out[(size_t)i * 3 + 1] = 1.0f / (1.0f + expf(-a1));
        out[(size_t)i * 3 + 2] = 1.0f / (1.0f + expf(-a2));
    }
}

// ---------------- launcher ----------------

extern "C" void kernel_launch(void* const* d_in, const int* in_sizes, int n_in,
                              void* d_out, int out_size, void* d_ws, size_t ws_size,
                              hipStream_t stream)
{
    const float* x   = (const float*)d_in[0];
    const int*   ei  = (const int*)d_in[1];
    const float* W1  = (const float*)d_in[2];
    const float* b1  = (const float*)d_in[3];
    const float* W2  = (const float*)d_in[4];
    const float* b2  = (const float*)d_in[5];
    const float* Wfc = (const float*)d_in[6];
    const float* bfc = (const float*)d_in[7];
    float* out = (float*)d_out;

    const int n = in_sizes[0] / D_IN;       // 100000
    const int e = in_sizes[1] / 2;          // 3200000
    const int* src = ei;
    const int* dst = ei + e;

    // workspace layout (floats): norm | h1 (later agg2) | agg1 | h2
    size_t nAl = ((size_t)n + 63) & ~(size_t)63;
    float* norm = (float*)d_ws;
    float* h1   = norm + nAl;
    float* agg1 = h1 + (size_t)n * H_DIM;
    float* h2   = agg1 + (size_t)n * H_DIM;
    float* agg2 = h1;   // h1 dead after scatter1

    const int nb_n = (n + 255) / 256;
    const int nb_e = (e + 255) / 256;
    const int nb_s = (int)(((long long)e * 32 + 255) / 256);

    k_init_deg<<<nb_n, 256, 0, stream>>>(norm, n);
    k_count_deg<<<nb_e, 256, 0, stream>>>(dst, norm, e);
    k_norm<<<nb_n, 256, 0, stream>>>(norm, n);

    k_gemm1<<<nb_n, 256, 0, stream>>>(x, W1, norm, h1, agg1, n);
    k_scatter<<<nb_s, 256, 0, stream>>>(h1, norm, src, dst, agg1, e);

    k_gemm2<<<nb_n, 256, 0, stream>>>(agg1, b1, W2, norm, h2, agg2, n);
    k_scatter<<<nb_s, 256, 0, stream>>>(h2, norm, src, dst, agg2, e);

    k_final<<<nb_n, 256, 0, stream>>>(agg2, b2, Wfc, bfc, out, n);
}